// Round 1
// baseline (1211.043 us; speedup 1.0000x reference)
//
#include <hip/hip_runtime.h>

// Seq2SeqRNN v6: fix register-pressure spill + pipeline input staging.
// v5 kept 6 k-chunks of gate weights "in VGPR" (144 regs) -> didn't fit the
// 256-reg unified budget at 2 waves/SIMD -> AGPR shuffles/scratch reloads each
// step (VALUBusy 34%/active-CU, 13.2K cyc/step). v6: 4 VGPR chunks (96 regs),
// chunks 4,5 join the L2-streamed set (W2 image extended to k=128..351).
// Input staging (num/cat/emb) prefetched 1-2 steps ahead; out-store moved
// after B2 so its drain overlaps gate compute.

#define BATCH 512
#define TSEQ  192
#define LIN_  96
#define LOUT_ 96
#define NUM_  64
#define EMB_  32
#define HID_  256
#define INS_  96

#define NBLK  32
#define NT    512          // 8 waves, 2/SIMD -> 256 unified VGPR budget
#define XSTR  360          // bf16 stride, XH[16][x(96)|h(256)] rows (720 B, 16B-aligned)
#define WLSTR 72           // bf16 stride, WL rows (144 B, 16B-aligned)
#define WDSTR 264          // bf16 stride, WD rows (528 B, 16B-aligned)

// ws layout: bf16 image of W cols k=128..351 (chunks 4..10) + W_dec image.
// W2[768][224]: col c <-> k=128+c <-> W_hh col 32+c. All blocks share it (L2-hot).
#define WS_W2   0u          // 768*224*2 = 344064 B
#define WS_WDEC 344064u     // [64][256] bf16 = 32768 B
#define WS_NEED 376832u     // <= 516KB proven available

typedef __attribute__((ext_vector_type(8))) short short8_t;
typedef __attribute__((ext_vector_type(4))) float float4_t;
typedef unsigned short us;

__device__ __forceinline__ us f2bf(float x) {
    unsigned u = __builtin_bit_cast(unsigned, x);
    u = (u + 0x7FFFu + ((u >> 16) & 1u)) >> 16;
    return (us)u;
}
__device__ __forceinline__ float sigm(float x)  { return 1.0f / (1.0f + __expf(-x)); }
__device__ __forceinline__ float tanhx(float x) { return 2.0f / (1.0f + __expf(-2.0f * x)) - 1.0f; }

__device__ __forceinline__ short8_t pack8(const float* v) {
    short8_t s;
    #pragma unroll
    for (int j = 0; j < 8; ++j) s[j] = (short)f2bf(v[j]);
    return s;
}

#define MFMA16(a, b, c) __builtin_amdgcn_mfma_f32_16x16x32_bf16((a), (b), (c), 0, 0, 0)

// ============ prep: bf16 images of streamed weight slice (k=128..351) + W_dec ============
__global__ void prep_v6(const float* __restrict__ W_hh, const float* __restrict__ W_dec,
                        unsigned char* __restrict__ ws) {
    us* W2    = (us*)(ws + WS_W2);      // [768][224]: col c <-> W_hh col 32+c
    us* WdecB = (us*)(ws + WS_WDEC);    // [64][256]
    const int i = blockIdx.x * 256 + threadIdx.x;
    if (i < 768 * 224) {
        const int row = i / 224, c = i - row * 224;
        W2[i] = f2bf(W_hh[row * HID_ + 32 + c]);
    } else if (i < 768 * 224 + 64 * 256) {
        const int x = i - 768 * 224;
        WdecB[x] = f2bf(W_dec[x]);
    }
}

// ============ main: one self-sufficient block per 16 batch rows ============
__global__ __launch_bounds__(NT, 2) void gru_v6(
    const float* __restrict__ input_num, const int* __restrict__ input_cat,
    const float* __restrict__ emb_table,
    const float* __restrict__ W_ih, const float* __restrict__ W_hh,
    const float* __restrict__ b_ih, const float* __restrict__ b_hh,
    const float* __restrict__ b_dec,
    const unsigned char* __restrict__ ws, float* __restrict__ out)
{
    __shared__ __align__(16) us XH[16 * XSTR];       // operand: [x 0..95 | h 96..351]
    __shared__ __align__(16) us WL[768 * WLSTR];     // gate-W k-chunks 6,7 (k=192..255)
    __shared__ __align__(16) us WD[64 * WDSTR];      // W_dec bf16

    const us* W2    = (const us*)(ws + WS_W2);
    const us* WdecB = (const us*)(ws + WS_WDEC);

    const int t = threadIdx.x, wave = t >> 6, lane = t & 63;
    const int arow = lane & 15, quad = lane >> 4, kq = quad * 8;
    const int bb = blockIdx.x * 16;

    // ---- one-time: VGPR gate-weight frags, k-chunks 0..3 only (96 regs) ----
    short8_t wfr[2][3][4];
    #pragma unroll
    for (int ti = 0; ti < 2; ++ti) {
        #pragma unroll
        for (int g3 = 0; g3 < 3; ++g3) {
            const int grow = g3 * HID_ + 32 * wave + 16 * ti + arow;
            #pragma unroll
            for (int kc = 0; kc < 4; ++kc) {
                float tmp[8];
                #pragma unroll
                for (int j2 = 0; j2 < 2; ++j2) {
                    const int k = kc * 32 + kq + j2 * 4;   // < 128; never straddles 96
                    float4 v = (k < INS_)
                        ? *(const float4*)&W_ih[(size_t)grow * INS_ + k]
                        : *(const float4*)&W_hh[(size_t)grow * HID_ + (k - INS_)];
                    tmp[j2 * 4 + 0] = v.x; tmp[j2 * 4 + 1] = v.y;
                    tmp[j2 * 4 + 2] = v.z; tmp[j2 * 4 + 3] = v.w;
                }
                wfr[ti][g3][kc] = pack8(tmp);
            }
        }
    }

    // ---- one-time: LDS staging ----
    for (int c = t; c < 768 * 8; c += NT) {          // WL <- W2 cols 64..127 (k 192..255)
        const int row = c >> 3, q = c & 7;
        *(ulonglong2*)&WL[row * WLSTR + q * 8] = *(const ulonglong2*)&W2[row * 224 + 64 + q * 8];
    }
    for (int c = t; c < 64 * 32; c += NT) {          // WD <- WdecB
        const int row = c >> 5, q = c & 31;
        *(ulonglong2*)&WD[row * WDSTR + q * 8] = *(const ulonglong2*)&WdecB[row * 256 + q * 8];
    }
    for (int c = t; c < 16 * XSTR; c += NT) XH[c] = 0;

    // ---- one-time: per-lane biases (unit u = 32w + 16ti + (lane&15)) ----
    float bRr[2], bZr[2], bNXr[2], bNHr[2];
    #pragma unroll
    for (int ti = 0; ti < 2; ++ti) {
        const int u = 32 * wave + 16 * ti + arow;
        bRr[ti]  = b_ih[u] + b_hh[u];
        bZr[ti]  = b_ih[HID_ + u] + b_hh[HID_ + u];
        bNXr[ti] = b_ih[2 * HID_ + u];
        bNHr[ti] = b_hh[2 * HID_ + u];
    }
    const float bdr = (wave < 4) ? b_dec[wave * 16 + arow] : 0.0f;
    float hr[2][4] = {{0.f,0.f,0.f,0.f},{0.f,0.f,0.f,0.f}};

    // ---- input staging pipeline registers (prefetch 1 step ahead, cat 2 ahead) ----
    // roles: t<256 -> num (enc only), 256<=t<384 -> emb (all steps)
    const int srow = (t < 256) ? (t >> 4) : ((t - 256) >> 3);
    const int sq   = (t < 256) ? (t & 15) : ((t - 256) & 7);
    float4 pnum = {0.f, 0.f, 0.f, 0.f};
    float4 pemb = {0.f, 0.f, 0.f, 0.f};
    int pcat = 0;
    if (t < 256) {
        pnum = *(const float4*)&input_num[((size_t)(bb + srow) * TSEQ + 0) * NUM_ + sq * 4];
    } else if (t < 384) {
        const int c0 = input_cat[(bb + srow) * TSEQ + 0];
        pemb = *(const float4*)&emb_table[(size_t)c0 * EMB_ + sq * 4];
        pcat = input_cat[(bb + srow) * TSEQ + 1];
    }
    __syncthreads();

    // ======== 191 sequential GRU steps, all block-local ========
    for (int sg = 1; sg <= 191; ++sg) {
        // (A) stage x from pipeline regs: enc = num(0..63)+emb(64..95); dec = emb only
        if (t < 256) {
            if (sg <= 96) {
                ushort4 s = { f2bf(pnum.x), f2bf(pnum.y), f2bf(pnum.z), f2bf(pnum.w) };
                *(ushort4*)&XH[srow * XSTR + sq * 4] = s;
            }
        } else if (t < 384) {
            ushort4 s = { f2bf(pemb.x), f2bf(pemb.y), f2bf(pemb.z), f2bf(pemb.w) };
            *(ushort4*)&XH[srow * XSTR + NUM_ + sq * 4] = s;
        }
        __syncthreads();   // B1: x + prev h visible

        // (C) decoder: out_{sg-97} = h_{sg-1} @ W_dec^T + b_dec; feedback -> XH[0..63]
        float oval[4];
        if (sg > 96) {
            if (wave < 4) {
                float4_t acc = {0.f, 0.f, 0.f, 0.f};
                #pragma unroll
                for (int kc = 0; kc < 8; ++kc) {
                    short8_t a = *(const short8_t*)&XH[arow * XSTR + INS_ + kc * 32 + kq];
                    short8_t b = *(const short8_t*)&WD[(wave * 16 + arow) * WDSTR + kc * 32 + kq];
                    acc = MFMA16(a, b, acc);
                }
                const int cg = wave * 16 + arow;
                #pragma unroll
                for (int i = 0; i < 4; ++i) {
                    const int row = quad * 4 + i;
                    oval[i] = acc[i] + bdr;
                    XH[row * XSTR + cg] = f2bf(oval[i]);   // feedback (LDS, cheap)
                }
            }
            __syncthreads();   // B2: feedback visible
            if (wave < 4) {    // global store AFTER B2: drain overlaps gate compute
                const int cg = wave * 16 + arow, pos = sg - 97;
                #pragma unroll
                for (int i = 0; i < 4; ++i)
                    out[((size_t)(bb + quad * 4 + i) * LOUT_ + pos) * NUM_ + cg] = oval[i];
            }
        }

        // prefetch next step's inputs now; drains at B3, hidden under gate MFMAs
        if (sg <= 190) {
            if (t < 256) {
                if (sg < 96)
                    pnum = *(const float4*)&input_num[((size_t)(bb + srow) * TSEQ + sg) * NUM_ + sq * 4];
            } else if (t < 384) {
                pemb = *(const float4*)&emb_table[(size_t)pcat * EMB_ + sq * 4];
                if (sg < 190) pcat = input_cat[(bb + srow) * TSEQ + sg + 1];
            }
        }

        // (D)+(E) gates + pure-register pointwise, per unit-tile
        // k-chunks: 0..3 VGPR | 4,5 streamed | 6,7 LDS | 8..10 streamed
        #pragma unroll
        for (int ti = 0; ti < 2; ++ti) {
            short8_t sw[3][5];   // streamed B-frags: s=0,1 -> chunks 4,5; s=2..4 -> 8..10
            #pragma unroll
            for (int g3 = 0; g3 < 3; ++g3) {
                const int grow = g3 * HID_ + 32 * wave + 16 * ti + arow;
                #pragma unroll
                for (int s = 0; s < 5; ++s) {
                    const int col = (s < 2) ? s * 32 : (s + 2) * 32;   // W2 cols {0,32,128,160,192}
                    sw[g3][s] = *(const short8_t*)&W2[(size_t)grow * 224 + col + kq];
                }
            }
            float4_t aR = {0.f,0.f,0.f,0.f}, aZ = {0.f,0.f,0.f,0.f};
            float4_t aNX = {0.f,0.f,0.f,0.f}, aNH = {0.f,0.f,0.f,0.f};
            #pragma unroll
            for (int kc = 0; kc < 4; ++kc) {          // VGPR-resident chunks
                short8_t a = *(const short8_t*)&XH[arow * XSTR + kc * 32 + kq];
                aR = MFMA16(a, wfr[ti][0][kc], aR);
                aZ = MFMA16(a, wfr[ti][1][kc], aZ);
                if (kc < 3) aNX = MFMA16(a, wfr[ti][2][kc], aNX);   // x-part of n
                else        aNH = MFMA16(a, wfr[ti][2][kc], aNH);   // h-part of n
            }
            #pragma unroll
            for (int s = 0; s < 2; ++s) {             // streamed chunks 4,5 (k=128..191)
                short8_t a = *(const short8_t*)&XH[arow * XSTR + (4 + s) * 32 + kq];
                aR = MFMA16(a, sw[0][s], aR);
                aZ = MFMA16(a, sw[1][s], aZ);
                aNH = MFMA16(a, sw[2][s], aNH);
            }
            #pragma unroll
            for (int kc = 6; kc < 8; ++kc) {          // LDS-resident chunks (k=192..255)
                short8_t a = *(const short8_t*)&XH[arow * XSTR + kc * 32 + kq];
                const int wbase = 32 * wave + 16 * ti + arow;
                short8_t b0 = *(const short8_t*)&WL[(0 * HID_ + wbase) * WLSTR + (kc - 6) * 32 + kq];
                short8_t b1 = *(const short8_t*)&WL[(1 * HID_ + wbase) * WLSTR + (kc - 6) * 32 + kq];
                short8_t b2 = *(const short8_t*)&WL[(2 * HID_ + wbase) * WLSTR + (kc - 6) * 32 + kq];
                aR = MFMA16(a, b0, aR);
                aZ = MFMA16(a, b1, aZ);
                aNH = MFMA16(a, b2, aNH);
            }
            #pragma unroll
            for (int s = 2; s < 5; ++s) {             // streamed chunks 8..10 (k=256..351)
                short8_t a = *(const short8_t*)&XH[arow * XSTR + (s + 6) * 32 + kq];
                aR = MFMA16(a, sw[0][s], aR);
                aZ = MFMA16(a, sw[1][s], aZ);
                aNH = MFMA16(a, sw[2][s], aNH);
            }
            // pointwise GRU cell (in-register; C-frag: unit=32w+16ti+arow, row=quad*4+i)
            #pragma unroll
            for (int i = 0; i < 4; ++i) {
                const float r = sigm(aR[i] + bRr[ti]);
                const float z = sigm(aZ[i] + bZr[ti]);
                const float n = tanhx(aNX[i] + bNXr[ti] + r * (aNH[i] + bNHr[ti]));
                hr[ti][i] = (1.0f - z) * n + z * hr[ti][i];
            }
        }
        __syncthreads();   // B3: all waves done reading XH h-cols
        #pragma unroll
        for (int ti = 0; ti < 2; ++ti) {
            #pragma unroll
            for (int i = 0; i < 4; ++i)
                XH[(quad * 4 + i) * XSTR + INS_ + 32 * wave + 16 * ti + arow] = f2bf(hr[ti][i]);
        }
    }

    // ======== epilogue: out position 95 from h_191 ========
    __syncthreads();
    if (wave < 4) {
        float4_t acc = {0.f, 0.f, 0.f, 0.f};
        #pragma unroll
        for (int kc = 0; kc < 8; ++kc) {
            short8_t a = *(const short8_t*)&XH[arow * XSTR + INS_ + kc * 32 + kq];
            short8_t b = *(const short8_t*)&WD[(wave * 16 + arow) * WDSTR + kc * 32 + kq];
            acc = MFMA16(a, b, acc);
        }
        const int cg = wave * 16 + arow;
        #pragma unroll
        for (int i = 0; i < 4; ++i) {
            const int row = quad * 4 + i;
            out[((size_t)(bb + row) * LOUT_ + 95) * NUM_ + cg] = acc[i] + bdr;
        }
    }
}

// ============ fallback (v1 logic, known-passing fp32) if ws too small ============
__global__ __launch_bounds__(512) void gru_fallback(
    const float* __restrict__ input_num, const int* __restrict__ input_cat,
    const float* __restrict__ emb_table,
    const float* __restrict__ W_ih, const float* __restrict__ W_hh,
    const float* __restrict__ b_ih, const float* __restrict__ b_hh,
    const float* __restrict__ W_dec, const float* __restrict__ b_dec,
    float* __restrict__ out)
{
    __shared__ __align__(16) float xh[4][352];
    __shared__ float wdec[NUM_ * 257];
    const int t = threadIdx.x, bbase = blockIdx.x * 4;
    const int u = t & 255, rb = (t >> 8) * 2;
    for (int i = t; i < NUM_ * HID_; i += 512) wdec[(i >> 8) * 257 + (i & 255)] = W_dec[i];
    for (int i = t; i < 4 * HID_; i += 512) xh[i >> 8][INS_ + (i & 255)] = 0.0f;
    const float bR = b_ih[u] + b_hh[u], bZ = b_ih[256 + u] + b_hh[256 + u];
    const float bNX = b_ih[512 + u], bNH = b_hh[512 + u], bD = b_dec[t & 63];
    __syncthreads();
    auto step = [&]() {
        float aR0 = bR, aR1 = bR, aZ0 = bZ, aZ1 = bZ, aNX0 = bNX, aNX1 = bNX, aNH0 = bNH, aNH1 = bNH;
        const float* x0 = xh[rb]; const float* x1 = xh[rb + 1];
        for (int kb = 0; kb < 88; ++kb) {
            float4 w0, w1, w2; int k4 = kb * 4;
            if (k4 < INS_) {
                w0 = *(const float4*)&W_ih[(size_t)u * INS_ + k4];
                w1 = *(const float4*)&W_ih[(size_t)(256 + u) * INS_ + k4];
                w2 = *(const float4*)&W_ih[(size_t)(512 + u) * INS_ + k4];
            } else {
                int kh = k4 - INS_;
                w0 = *(const float4*)&W_hh[(size_t)u * HID_ + kh];
                w1 = *(const float4*)&W_hh[(size_t)(256 + u) * HID_ + kh];
                w2 = *(const float4*)&W_hh[(size_t)(512 + u) * HID_ + kh];
            }
            float4 a = *(const float4*)&x0[k4], c = *(const float4*)&x1[k4];
            aR0 += w0.x*a.x+w0.y*a.y+w0.z*a.z+w0.w*a.w; aR1 += w0.x*c.x+w0.y*c.y+w0.z*c.z+w0.w*c.w;
            aZ0 += w1.x*a.x+w1.y*a.y+w1.z*a.z+w1.w*a.w; aZ1 += w1.x*c.x+w1.y*c.y+w1.z*c.z+w1.w*c.w;
            if (k4 < INS_) { aNX0 += w2.x*a.x+w2.y*a.y+w2.z*a.z+w2.w*a.w; aNX1 += w2.x*c.x+w2.y*c.y+w2.z*c.z+w2.w*c.w; }
            else           { aNH0 += w2.x*a.x+w2.y*a.y+w2.z*a.z+w2.w*a.w; aNH1 += w2.x*c.x+w2.y*c.y+w2.z*c.z+w2.w*c.w; }
        }
        float h0 = x0[INS_ + u], h1 = x1[INS_ + u];
        __syncthreads();
        { float r = sigm(aR0), z = sigm(aZ0), n = tanhx(aNX0 + r * aNH0);
          xh[rb][INS_ + u] = (1 - z) * n + z * h0; }
        { float r = sigm(aR1), z = sigm(aZ1), n = tanhx(aNX1 + r * aNH1);
          xh[rb + 1][INS_ + u] = (1 - z) * n + z * h1; }
        __syncthreads();
    };
    auto project = [&](int pos) {
        if (t < 256) {
            int r = t >> 6, m = t & 63;
            const float* wr = &wdec[m * 257]; const float* hr2 = &xh[r][INS_];
            float acc = bD;
            for (int k = 0; k < HID_; ++k) acc = fmaf(wr[k], hr2[k], acc);
            out[((size_t)(bbase + r) * LOUT_ + pos) * NUM_ + m] = acc;
            xh[r][m] = acc;
        }
    };
    for (int s = 0; s < LIN_; ++s) {
        if (t < 256) { int r = t >> 6, k = t & 63;
            xh[r][k] = input_num[((size_t)(bbase + r) * TSEQ + s) * NUM_ + k]; }
        if (t < 128) { int r = t >> 5, e = t & 31;
            xh[r][NUM_ + e] = emb_table[input_cat[(bbase + r) * TSEQ + s] * EMB_ + e]; }
        __syncthreads();
        step();
    }
    project(0);
    for (int s = 0; s < LOUT_ - 1; ++s) {
        if (t < 128) { int r = t >> 5, e = t & 31;
            xh[r][NUM_ + e] = emb_table[input_cat[(bbase + r) * TSEQ + LIN_ + s] * EMB_ + e]; }
        __syncthreads();
        step();
        project(s + 1);
    }
}

extern "C" void kernel_launch(void* const* d_in, const int* in_sizes, int n_in,
                              void* d_out, int out_size, void* d_ws, size_t ws_size,
                              hipStream_t stream) {
    const float* input_num = (const float*)d_in[0];
    const int*   input_cat = (const int*)d_in[1];
    const float* emb_table = (const float*)d_in[2];
    const float* W_ih      = (const float*)d_in[3];
    const float* W_hh      = (const float*)d_in[4];
    const float* b_ih      = (const float*)d_in[5];
    const float* b_hh      = (const float*)d_in[6];
    const float* W_dec     = (const float*)d_in[7];
    const float* b_dec     = (const float*)d_in[8];
    float* out = (float*)d_out;

    if (ws_size >= WS_NEED) {
        unsigned char* ws = (unsigned char*)d_ws;
        const int PREP_N = 768 * 224 + 64 * 256;
        prep_v6<<<(PREP_N + 255) / 256, 256, 0, stream>>>(W_hh, W_dec, ws);
        gru_v6<<<NBLK, NT, 0, stream>>>(input_num, input_cat, emb_table,
                                        W_ih, W_hh, b_ih, b_hh, b_dec, ws, out);
    } else {
        gru_fallback<<<BATCH / 4, 512, 0, stream>>>(input_num, input_cat, emb_table,
                                                    W_ih, W_hh, b_ih, b_hh, W_dec, b_dec, out);
    }
}

// Round 2
// 1184.955 us; speedup vs baseline: 1.0220x; 1.0220x over previous
//
#include <hip/hip_runtime.h>

// Seq2SeqRNN v7: v5 skeleton (8 waves x 2 unit-tiles, c0..5 in reg frags) with
// (1) fragment-linear weight images: every streamed/LDS/W_dec B-frag stored as a
//     contiguous 1KB block (lane l -> bytes l*16..+16) -> coalesced 1KB wave loads
//     from L2, conflict-free ds_read_b128 from LDS.
// (2) barrier restructure: num/emb/h double-buffered in XH -> encoder 1 barrier/step
//     (was 2), decode 2 (was 3). fb reuses dead num0 slot.
// (3) prefetch issue placement: encoder at step-top, decode post-B2; out-store post-B2.
// v6 lesson: reg(AGPR)-resident weights are free; streamed loads are the cost.

#define BATCH 512
#define TSEQ  192
#define LIN_  96
#define LOUT_ 96
#define NUM_  64
#define EMB_  32
#define HID_  256
#define INS_  96

#define NBLK  32
#define NT    512          // 8 waves, 2/SIMD

// XH row layout (us cols): [fb/num0 64 | num1 64 | e0 32 | e1 32 | h0 256 | h1 256]
#define XSTR  712          // us stride (1424 B, 16B aligned; /2 mod 32 = 4 -> even banks)
#define XFB   0
#define XNUM0 0
#define XNUM1 64
#define XEMB0 128
#define XEMB1 160
#define XHB   192          // h0 @192, h1 @448

// ws layout: fragment-linear bf16 images (1024 B per frag, lane-major)
//  WL  (LDS-staged): rz c6..8 (idx g*48+tt*3+cs, g<2), n c6..7 (idx 96+tt*2+cs) = 128 frags
//  WS  (streamed)  : rz c9..10 (idx g*32+tt*2+s), n c8..10 (idx 64+tt*3+s)      = 112 frags
//  WD  (W_dec)     : idx tt*8+c (tt<4, c<8)                                      = 32 frags
#define WS_WL   0u
#define WS_WS   131072u
#define WS_WD   245760u
#define WS_NEED 278528u

typedef __attribute__((ext_vector_type(8))) short short8_t;
typedef __attribute__((ext_vector_type(4))) float float4_t;
typedef unsigned short us;

__device__ __forceinline__ us f2bf(float x) {
    unsigned u = __builtin_bit_cast(unsigned, x);
    u = (u + 0x7FFFu + ((u >> 16) & 1u)) >> 16;
    return (us)u;
}
__device__ __forceinline__ float sigm(float x)  { return 1.0f / (1.0f + __expf(-x)); }
__device__ __forceinline__ float tanhx(float x) { return 2.0f / (1.0f + __expf(-2.0f * x)) - 1.0f; }

__device__ __forceinline__ short8_t pack8(const float* v) {
    short8_t s;
    #pragma unroll
    for (int j = 0; j < 8; ++j) s[j] = (short)f2bf(v[j]);
    return s;
}

#define MFMA16(a, b, c) __builtin_amdgcn_mfma_f32_16x16x32_bf16((a), (b), (c), 0, 0, 0)

// ============ prep: fragment-linear bf16 weight images ============
__global__ void prep_v7(const float* __restrict__ W_ih, const float* __restrict__ W_hh,
                        const float* __restrict__ W_dec, unsigned char* __restrict__ ws) {
    us* WLi = (us*)(ws + WS_WL);
    us* WSi = (us*)(ws + WS_WS);
    us* WDi = (us*)(ws + WS_WD);
    const int idx = blockIdx.x * 256 + threadIdx.x;
    if (idx >= 272 * 64) return;
    const int f = idx >> 6, l = idx & 63;
    const int r16 = l & 15, kq8 = (l >> 4) * 8;
    float tmp[8];
    if (f < 240) {
        int grow, k;
        us* dst;
        if (f < 128) {                       // WL frags (c = 6..8 rz, 6..7 n)
            if (f < 96) { const int g = f / 48, rem = f % 48, tt = rem / 3, cs = rem % 3;
                grow = g * 256 + tt * 16 + r16; k = (6 + cs) * 32 + kq8; }
            else { const int f2 = f - 96, tt = f2 >> 1, cs = f2 & 1;
                grow = 512 + tt * 16 + r16; k = (6 + cs) * 32 + kq8; }
            dst = WLi + f * 512 + l * 8;
        } else {                             // WS stream frags (c = 9..10 rz, 8..10 n)
            const int s = f - 128;
            if (s < 64) { const int g = s >> 5, rem = s & 31, tt = rem >> 1;
                grow = g * 256 + tt * 16 + r16; k = (9 + (rem & 1)) * 32 + kq8; }
            else { const int s2 = s - 64, tt = s2 / 3;
                grow = 512 + tt * 16 + r16; k = (8 + s2 % 3) * 32 + kq8; }
            dst = WSi + s * 512 + l * 8;
        }
        // all these frags have k >= 192 >= 96 -> W_hh
        #pragma unroll
        for (int j = 0; j < 8; ++j) tmp[j] = W_hh[(size_t)grow * HID_ + (k - INS_) + j];
        *(short8_t*)dst = pack8(tmp);
    } else {                                 // WD frags
        const int f3 = f - 240, tt = f3 >> 3, c = f3 & 7;
        const int urow = tt * 16 + r16, k = c * 32 + kq8;
        #pragma unroll
        for (int j = 0; j < 8; ++j) tmp[j] = W_dec[(size_t)urow * HID_ + k + j];
        *(short8_t*)(WDi + f3 * 512 + l * 8) = pack8(tmp);
    }
}

// ============ main ============
__global__ __launch_bounds__(NT, 2) void gru_v7(
    const float* __restrict__ input_num, const int* __restrict__ input_cat,
    const float* __restrict__ emb_table,
    const float* __restrict__ W_ih, const float* __restrict__ W_hh,
    const float* __restrict__ b_ih, const float* __restrict__ b_hh,
    const float* __restrict__ b_dec,
    const unsigned char* __restrict__ ws, float* __restrict__ out)
{
    __shared__ __align__(16) us XH[16 * XSTR];
    __shared__ __align__(16) us WL[128 * 512];

    const us* WSs = (const us*)(ws + WS_WS);
    const us* WDf = (const us*)(ws + WS_WD);
    const us* WLi = (const us*)(ws + WS_WL);

    const int t = threadIdx.x, wave = t >> 6, lane = t & 63;
    const int arow = lane & 15, quad = lane >> 4, kq = quad * 8;
    const int bb = blockIdx.x * 16;

    // ---- one-time: VGPR/AGPR gate-weight frags, chunks 0..5 (fp32 -> bf16) ----
    short8_t wfr[2][3][6];
    #pragma unroll
    for (int ti = 0; ti < 2; ++ti) {
        #pragma unroll
        for (int g3 = 0; g3 < 3; ++g3) {
            const int grow = g3 * HID_ + 32 * wave + 16 * ti + arow;
            #pragma unroll
            for (int kc = 0; kc < 6; ++kc) {
                float tmp[8];
                #pragma unroll
                for (int j2 = 0; j2 < 2; ++j2) {
                    const int k = kc * 32 + kq + j2 * 4;   // < 192; never straddles 96
                    float4 v = (k < INS_)
                        ? *(const float4*)&W_ih[(size_t)grow * INS_ + k]
                        : *(const float4*)&W_hh[(size_t)grow * HID_ + (k - INS_)];
                    tmp[j2 * 4 + 0] = v.x; tmp[j2 * 4 + 1] = v.y;
                    tmp[j2 * 4 + 2] = v.z; tmp[j2 * 4 + 3] = v.w;
                }
                wfr[ti][g3][kc] = pack8(tmp);
            }
        }
    }

    // ---- one-time: LDS staging (fragment-linear copy) + XH zero ----
    for (int c = t; c < 8192; c += NT)
        *(ulonglong2*)&WL[c * 8] = *(const ulonglong2*)&WLi[c * 8];
    for (int c = t; c < 16 * XSTR; c += NT) XH[c] = 0;

    // ---- biases ----
    float bRr[2], bZr[2], bNXr[2], bNHr[2];
    #pragma unroll
    for (int ti = 0; ti < 2; ++ti) {
        const int u = 32 * wave + 16 * ti + arow;
        bRr[ti]  = b_ih[u] + b_hh[u];
        bZr[ti]  = b_ih[HID_ + u] + b_hh[HID_ + u];
        bNXr[ti] = b_ih[2 * HID_ + u];
        bNHr[ti] = b_hh[2 * HID_ + u];
    }
    const float bdr = (wave < 4) ? b_dec[wave * 16 + arow] : 0.0f;
    float hr[2][4] = {{0.f,0.f,0.f,0.f},{0.f,0.f,0.f,0.f}};

    // ---- staging roles + initial stage of x_0 into bufs[0] ----
    const int srow = t >> 4, sq = t & 15;                    // num role: t<256
    const int erow = (t - 256) >> 3, eq = (t - 256) & 7;     // emb role: 256<=t<384
    const bool isN = (t < 256), isE = (t >= 256 && t < 384);
    float4 pnum = {0.f,0.f,0.f,0.f}, pemb = {0.f,0.f,0.f,0.f};
    int pcat = 0;

    if (isN) {
        float4 v = *(const float4*)&input_num[((size_t)(bb + srow) * TSEQ + 0) * NUM_ + sq * 4];
        ushort4 s4 = { f2bf(v.x), f2bf(v.y), f2bf(v.z), f2bf(v.w) };
        *(ushort4*)&XH[srow * XSTR + XNUM0 + sq * 4] = s4;
    } else if (isE) {
        const int c0 = input_cat[(bb + erow) * TSEQ + 0];
        float4 v = *(const float4*)&emb_table[(size_t)c0 * EMB_ + eq * 4];
        ushort4 s4 = { f2bf(v.x), f2bf(v.y), f2bf(v.z), f2bf(v.w) };
        *(ushort4*)&XH[erow * XSTR + XEMB0 + eq * 4] = s4;
        pcat = input_cat[(bb + erow) * TSEQ + 1];
    }
    __syncthreads();

    // ======== 191 sequential GRU steps ========
    for (int sg = 1; sg <= 191; ++sg) {
        const int bx = (sg - 1) & 1, hn = sg & 1;
        const int hbase = XHB + ((sg - 1) & 1) * 256;
        float oval[4];

        if (sg <= 96) {
            // encoder: prefetch at step-top (drains at this step's single barrier)
            if (isN && sg <= 95)
                pnum = *(const float4*)&input_num[((size_t)(bb + srow) * TSEQ + sg) * NUM_ + sq * 4];
            if (isE) {
                pemb = *(const float4*)&emb_table[(size_t)pcat * EMB_ + eq * 4];
                pcat = input_cat[(bb + erow) * TSEQ + sg + 1];
            }
        } else {
            // decode: fb-projection out_prev = h_prev @ W_dec^T (waves 0..3)
            if (wave < 4) {
                short8_t wd[8];
                #pragma unroll
                for (int c = 0; c < 8; ++c)
                    wd[c] = *(const short8_t*)&WDf[(wave * 8 + c) * 512 + lane * 8];
                float4_t acc = {0.f,0.f,0.f,0.f};
                #pragma unroll
                for (int c = 0; c < 8; ++c) {
                    short8_t a = *(const short8_t*)&XH[arow * XSTR + hbase + c * 32 + kq];
                    acc = MFMA16(a, wd[c], acc);
                }
                #pragma unroll
                for (int i = 0; i < 4; ++i) {
                    oval[i] = acc[i] + bdr;
                    XH[(quad * 4 + i) * XSTR + XFB + wave * 16 + arow] = f2bf(oval[i]);
                }
            }
            __syncthreads();   // B2: feedback visible
            if (wave < 4) {    // out store after B2: drains at B3 with gate-phase slack
                const int cg = wave * 16 + arow, pos = sg - 97;
                #pragma unroll
                for (int i = 0; i < 4; ++i)
                    out[((size_t)(bb + quad * 4 + i) * LOUT_ + pos) * NUM_ + cg] = oval[i];
            }
            // decode prefetch post-B2 (drains at B3 with gate-phase slack)
            if (isE && sg <= 190) {
                pemb = *(const float4*)&emb_table[(size_t)pcat * EMB_ + eq * 4];
                if (sg <= 189) pcat = input_cat[(bb + erow) * TSEQ + sg + 1];
            }
        }

        // ---- gates ----
        const int xc01 = (sg <= 96) ? (XNUM0 + bx * 64) : XFB;
        const int xc2  = XEMB0 + bx * 32;
        #pragma unroll
        for (int ti = 0; ti < 2; ++ti) {
            const int tt = 2 * wave + ti;
            // streamed B-frags (coalesced 1KB wave loads), issued first
            short8_t swR[2], swZ[2], swN[3];
            #pragma unroll
            for (int s = 0; s < 2; ++s) {
                swR[s] = *(const short8_t*)&WSs[(tt * 2 + s) * 512 + lane * 8];
                swZ[s] = *(const short8_t*)&WSs[((32 + tt) * 2 + s - tt * 0) * 512 + lane * 8];
            }
            // fix z index: idx = 32 + tt*2 + s
            swZ[0] = *(const short8_t*)&WSs[(32 + tt * 2 + 0) * 512 + lane * 8];
            swZ[1] = *(const short8_t*)&WSs[(32 + tt * 2 + 1) * 512 + lane * 8];
            #pragma unroll
            for (int s = 0; s < 3; ++s)
                swN[s] = *(const short8_t*)&WSs[(64 + tt * 3 + s) * 512 + lane * 8];
            // LDS B-frags (conflict-free fragment-linear)
            short8_t blR[3], blZ[3], blN[2];
            #pragma unroll
            for (int cs = 0; cs < 3; ++cs) {
                blR[cs] = *(const short8_t*)&WL[(tt * 3 + cs) * 512 + lane * 8];
                blZ[cs] = *(const short8_t*)&WL[(48 + tt * 3 + cs) * 512 + lane * 8];
            }
            #pragma unroll
            for (int cs = 0; cs < 2; ++cs)
                blN[cs] = *(const short8_t*)&WL[(96 + tt * 2 + cs) * 512 + lane * 8];

            float4_t aR = {0.f,0.f,0.f,0.f}, aZ = {0.f,0.f,0.f,0.f};
            float4_t aNX = {0.f,0.f,0.f,0.f}, aNH = {0.f,0.f,0.f,0.f};
            short8_t a;
            // c0..2: x part (reg weights)
            a = *(const short8_t*)&XH[arow * XSTR + xc01 + kq];
            aR = MFMA16(a, wfr[ti][0][0], aR); aZ = MFMA16(a, wfr[ti][1][0], aZ); aNX = MFMA16(a, wfr[ti][2][0], aNX);
            a = *(const short8_t*)&XH[arow * XSTR + xc01 + 32 + kq];
            aR = MFMA16(a, wfr[ti][0][1], aR); aZ = MFMA16(a, wfr[ti][1][1], aZ); aNX = MFMA16(a, wfr[ti][2][1], aNX);
            a = *(const short8_t*)&XH[arow * XSTR + xc2 + kq];
            aR = MFMA16(a, wfr[ti][0][2], aR); aZ = MFMA16(a, wfr[ti][1][2], aZ); aNX = MFMA16(a, wfr[ti][2][2], aNX);
            // c3..5: h part (reg weights)
            a = *(const short8_t*)&XH[arow * XSTR + hbase + 0 * 32 + kq];
            aR = MFMA16(a, wfr[ti][0][3], aR); aZ = MFMA16(a, wfr[ti][1][3], aZ); aNH = MFMA16(a, wfr[ti][2][3], aNH);
            a = *(const short8_t*)&XH[arow * XSTR + hbase + 1 * 32 + kq];
            aR = MFMA16(a, wfr[ti][0][4], aR); aZ = MFMA16(a, wfr[ti][1][4], aZ); aNH = MFMA16(a, wfr[ti][2][4], aNH);
            a = *(const short8_t*)&XH[arow * XSTR + hbase + 2 * 32 + kq];
            aR = MFMA16(a, wfr[ti][0][5], aR); aZ = MFMA16(a, wfr[ti][1][5], aZ); aNH = MFMA16(a, wfr[ti][2][5], aNH);
            // c6,7: LDS (rz + n)
            a = *(const short8_t*)&XH[arow * XSTR + hbase + 3 * 32 + kq];
            aR = MFMA16(a, blR[0], aR); aZ = MFMA16(a, blZ[0], aZ); aNH = MFMA16(a, blN[0], aNH);
            a = *(const short8_t*)&XH[arow * XSTR + hbase + 4 * 32 + kq];
            aR = MFMA16(a, blR[1], aR); aZ = MFMA16(a, blZ[1], aZ); aNH = MFMA16(a, blN[1], aNH);
            // c8: rz LDS, n streamed
            a = *(const short8_t*)&XH[arow * XSTR + hbase + 5 * 32 + kq];
            aR = MFMA16(a, blR[2], aR); aZ = MFMA16(a, blZ[2], aZ); aNH = MFMA16(a, swN[0], aNH);
            // c9,10: streamed
            a = *(const short8_t*)&XH[arow * XSTR + hbase + 6 * 32 + kq];
            aR = MFMA16(a, swR[0], aR); aZ = MFMA16(a, swZ[0], aZ); aNH = MFMA16(a, swN[1], aNH);
            a = *(const short8_t*)&XH[arow * XSTR + hbase + 7 * 32 + kq];
            aR = MFMA16(a, swR[1], aR); aZ = MFMA16(a, swZ[1], aZ); aNH = MFMA16(a, swN[2], aNH);

            // pointwise GRU cell (v5-exact numerics)
            #pragma unroll
            for (int i = 0; i < 4; ++i) {
                const float r = sigm(aR[i] + bRr[ti]);
                const float z = sigm(aZ[i] + bZr[ti]);
                const float n = tanhx(aNX[i] + bNXr[ti] + r * (aNH[i] + bNHr[ti]));
                hr[ti][i] = (1.0f - z) * n + z * hr[ti][i];
            }
        }

        // ---- write h[hn] + stage x_{sg} into bufs[sg&1] ----
        #pragma unroll
        for (int ti = 0; ti < 2; ++ti) {
            #pragma unroll
            for (int i = 0; i < 4; ++i)
                XH[(quad * 4 + i) * XSTR + XHB + hn * 256 + 32 * wave + 16 * ti + arow] = f2bf(hr[ti][i]);
        }
        if (sg <= 190) {
            if (isN && sg <= 95) {
                ushort4 s4 = { f2bf(pnum.x), f2bf(pnum.y), f2bf(pnum.z), f2bf(pnum.w) };
                *(ushort4*)&XH[srow * XSTR + XNUM0 + (sg & 1) * 64 + sq * 4] = s4;
            } else if (isE) {
                ushort4 s4 = { f2bf(pemb.x), f2bf(pemb.y), f2bf(pemb.z), f2bf(pemb.w) };
                *(ushort4*)&XH[erow * XSTR + XEMB0 + (sg & 1) * 32 + eq * 4] = s4;
            }
        }
        __syncthreads();   // B3 (single barrier for encoder steps)
    }

    // ======== epilogue: out position 95 from h_191 (in h buf 1) ========
    if (wave < 4) {
        float4_t acc = {0.f,0.f,0.f,0.f};
        #pragma unroll
        for (int c = 0; c < 8; ++c) {
            short8_t wd = *(const short8_t*)&WDf[(wave * 8 + c) * 512 + lane * 8];
            short8_t a  = *(const short8_t*)&XH[arow * XSTR + XHB + 256 + c * 32 + kq];
            acc = MFMA16(a, wd, acc);
        }
        const int cg = wave * 16 + arow;
        #pragma unroll
        for (int i = 0; i < 4; ++i)
            out[((size_t)(bb + quad * 4 + i) * LOUT_ + 95) * NUM_ + cg] = acc[i] + bdr;
    }
}

// ============ fallback (v1 logic, known-passing fp32) if ws too small ============
__global__ __launch_bounds__(512) void gru_fallback(
    const float* __restrict__ input_num, const int* __restrict__ input_cat,
    const float* __restrict__ emb_table,
    const float* __restrict__ W_ih, const float* __restrict__ W_hh,
    const float* __restrict__ b_ih, const float* __restrict__ b_hh,
    const float* __restrict__ W_dec, const float* __restrict__ b_dec,
    float* __restrict__ out)
{
    __shared__ __align__(16) float xh[4][352];
    __shared__ float wdec[NUM_ * 257];
    const int t = threadIdx.x, bbase = blockIdx.x * 4;
    const int u = t & 255, rb = (t >> 8) * 2;
    for (int i = t; i < NUM_ * HID_; i += 512) wdec[(i >> 8) * 257 + (i & 255)] = W_dec[i];
    for (int i = t; i < 4 * HID_; i += 512) xh[i >> 8][INS_ + (i & 255)] = 0.0f;
    const float bR = b_ih[u] + b_hh[u], bZ = b_ih[256 + u] + b_hh[256 + u];
    const float bNX = b_ih[512 + u], bNH = b_hh[512 + u], bD = b_dec[t & 63];
    __syncthreads();
    auto step = [&]() {
        float aR0 = bR, aR1 = bR, aZ0 = bZ, aZ1 = bZ, aNX0 = bNX, aNX1 = bNX, aNH0 = bNH, aNH1 = bNH;
        const float* x0 = xh[rb]; const float* x1 = xh[rb + 1];
        for (int kb = 0; kb < 88; ++kb) {
            float4 w0, w1, w2; int k4 = kb * 4;
            if (k4 < INS_) {
                w0 = *(const float4*)&W_ih[(size_t)u * INS_ + k4];
                w1 = *(const float4*)&W_ih[(size_t)(256 + u) * INS_ + k4];
                w2 = *(const float4*)&W_ih[(size_t)(512 + u) * INS_ + k4];
            } else {
                int kh = k4 - INS_;
                w0 = *(const float4*)&W_hh[(size_t)u * HID_ + kh];
                w1 = *(const float4*)&W_hh[(size_t)(256 + u) * HID_ + kh];
                w2 = *(const float4*)&W_hh[(size_t)(512 + u) * HID_ + kh];
            }
            float4 a = *(const float4*)&x0[k4], c = *(const float4*)&x1[k4];
            aR0 += w0.x*a.x+w0.y*a.y+w0.z*a.z+w0.w*a.w; aR1 += w0.x*c.x+w0.y*c.y+w0.z*c.z+w0.w*c.w;
            aZ0 += w1.x*a.x+w1.y*a.y+w1.z*a.z+w1.w*a.w; aZ1 += w1.x*c.x+w1.y*c.y+w1.z*c.z+w1.w*c.w;
            if (k4 < INS_) { aNX0 += w2.x*a.x+w2.y*a.y+w2.z*a.z+w2.w*a.w; aNX1 += w2.x*c.x+w2.y*c.y+w2.z*c.z+w2.w*c.w; }
            else           { aNH0 += w2.x*a.x+w2.y*a.y+w2.z*a.z+w2.w*a.w; aNH1 += w2.x*c.x+w2.y*c.y+w2.z*c.z+w2.w*c.w; }
        }
        float h0 = x0[INS_ + u], h1 = x1[INS_ + u];
        __syncthreads();
        { float r = sigm(aR0), z = sigm(aZ0), n = tanhx(aNX0 + r * aNH0);
          xh[rb][INS_ + u] = (1 - z) * n + z * h0; }
        { float r = sigm(aR1), z = sigm(aZ1), n = tanhx(aNX1 + r * aNH1);
          xh[rb + 1][INS_ + u] = (1 - z) * n + z * h1; }
        __syncthreads();
    };
    auto project = [&](int pos) {
        if (t < 256) {
            int r = t >> 6, m = t & 63;
            const float* wr = &wdec[m * 257]; const float* hr2 = &xh[r][INS_];
            float acc = bD;
            for (int k = 0; k < HID_; ++k) acc = fmaf(wr[k], hr2[k], acc);
            out[((size_t)(bbase + r) * LOUT_ + pos) * NUM_ + m] = acc;
            xh[r][m] = acc;
        }
    };
    for (int s = 0; s < LIN_; ++s) {
        if (t < 256) { int r = t >> 6, k = t & 63;
            xh[r][k] = input_num[((size_t)(bbase + r) * TSEQ + s) * NUM_ + k]; }
        if (t < 128) { int r = t >> 5, e = t & 31;
            xh[r][NUM_ + e] = emb_table[input_cat[(bbase + r) * TSEQ + s] * EMB_ + e]; }
        __syncthreads();
        step();
    }
    project(0);
    for (int s = 0; s < LOUT_ - 1; ++s) {
        if (t < 128) { int r = t >> 5, e = t & 31;
            xh[r][NUM_ + e] = emb_table[input_cat[(bbase + r) * TSEQ + LIN_ + s] * EMB_ + e]; }
        __syncthreads();
        step();
        project(s + 1);
    }
}

extern "C" void kernel_launch(void* const* d_in, const int* in_sizes, int n_in,
                              void* d_out, int out_size, void* d_ws, size_t ws_size,
                              hipStream_t stream) {
    const float* input_num = (const float*)d_in[0];
    const int*   input_cat = (const int*)d_in[1];
    const float* emb_table = (const float*)d_in[2];
    const float* W_ih      = (const float*)d_in[3];
    const float* W_hh      = (const float*)d_in[4];
    const float* b_ih      = (const float*)d_in[5];
    const float* b_hh      = (const float*)d_in[6];
    const float* W_dec     = (const float*)d_in[7];
    const float* b_dec     = (const float*)d_in[8];
    float* out = (float*)d_out;

    if (ws_size >= WS_NEED) {
        unsigned char* ws = (unsigned char*)d_ws;
        prep_v7<<<68, 256, 0, stream>>>(W_ih, W_hh, W_dec, ws);
        gru_v7<<<NBLK, NT, 0, stream>>>(input_num, input_cat, emb_table,
                                        W_ih, W_hh, b_ih, b_hh, b_dec, ws, out);
    } else {
        gru_fallback<<<BATCH / 4, 512, 0, stream>>>(input_num, input_cat, emb_table,
                                                    W_ih, W_hh, b_ih, b_hh, W_dec, b_dec, out);
    }
}